// Round 1
// baseline (203.190 us; speedup 1.0000x reference)
//
#include <hip/hip_runtime.h>
#include <math.h>

#define TEMP_INV 10.0f   // 1/0.1
#define EPS 1e-8f
#define B_ 256
#define P_ 32
#define N_ 512
#define D_ 256
#define K_ (P_ + N_)         // 544
#define CHUNK_ 16            // samples per wave
#define NCHUNK_ (K_ / CHUNK_) // 34 chunks per batch row; chunks 0,1 are the positives

__device__ __forceinline__ float dot4(float4 a, float4 b) {
    return a.x * b.x + a.y * b.y + a.z * b.z + a.w * b.w;
}

// sum over the 8-lane "sub" group (masks 1,2,4 — cheap intra-16 ds_swizzle).
// Every lane of the group ends with the group total.
__device__ __forceinline__ float reduce_sub8(float v) {
    v += __shfl_xor(v, 1, 64);
    v += __shfl_xor(v, 2, 64);
    v += __shfl_xor(v, 4, 64);
    return v;
}

// sum across the 8 sample-groups (masks 8,16,32): one 3-step butterfly
// reduces all 8 per-sample values at once.
__device__ __forceinline__ float reduce_grp8(float v) {
    v += __shfl_xor(v, 8, 64);
    v += __shfl_xor(v, 16, 64);
    v += __shfl_xor(v, 32, 64);
    return v;
}

// One wave per (b, chunk of 16 samples). 8 lanes own each sample:
// lane = (j = lane>>3 selects sample-within-tile, sub = lane&7 selects the
// 64-byte column slice). Per-lane register partial dots -> 3 cheap shuffles.
// Output: per-(b,chunk) partial  S = sum_k exp(sim_k - 10)  (fixed-shift LSE:
// sim = cos/0.1 <= 10 exactly, so exp(sim-10) in (0,1] — no max pass needed),
// plus sum of sims for the positive chunks (c < 2  <=>  k < 32 = P).
__global__ __launch_bounds__(256) void partial_kernel(
    const float* __restrict__ anchors,
    const float* __restrict__ positives,
    const float* __restrict__ negatives,
    float* __restrict__ S_ws,     // [NCHUNK_][B_] exp-sum partials
    float* __restrict__ POS_ws)   // [2][B_]      positive sim-sum partials
{
    int lane = threadIdx.x & 63;
    int gw   = blockIdx.x * 4 + (threadIdx.x >> 6);   // 0 .. B_*NCHUNK_-1 exactly
    int b = gw / NCHUNK_;
    int c = gw - b * NCHUNK_;
    int sub = lane & 7;
    int jj  = lane >> 3;

    // Anchor fragments: lane needs elements {p*32 + sub*4 + i}, p=0..7.
    // Same for every sample group -> loaded once, reused for 16 samples.
    // (union over sub of these = full 256 elems, so sub-reduce = full dot.)
    const float4* a4 = (const float4*)(anchors + (size_t)b * D_);
    float4 a[8];
    #pragma unroll
    for (int p = 0; p < 8; p++) a[p] = a4[p * 8 + sub];

    int k0 = c * CHUNK_;   // chunk is entirely positive (c<2) or entirely negative
    const float* base = (k0 < P_)
        ? positives + ((size_t)b * P_ + k0) * D_
        : negatives + ((size_t)b * N_ + (k0 - P_)) * D_;

    float napart = 0.f;
    #pragma unroll
    for (int p = 0; p < 8; p++) napart += dot4(a[p], a[p]);
    float na = sqrtf(reduce_sub8(napart));

    float e_acc = 0.f;
    float p_acc = 0.f;

    #pragma unroll
    for (int t = 0; t < 2; t++) {
        // 8 rows of 1 KB; per wave instruction: 8 contiguous 128 B segments
        // (same cache-line count as a fully contiguous 1 KB load).
        const float4* r = (const float4*)(base + (size_t)(t * 8 + jj) * D_);
        float4 s[8];
        #pragma unroll
        for (int p = 0; p < 8; p++) s[p] = r[p * 8 + sub];

        float dpart = 0.f, qpart = 0.f;
        #pragma unroll
        for (int p = 0; p < 8; p++) {
            dpart += dot4(a[p], s[p]);
            qpart += dot4(s[p], s[p]);
        }
        float dj = reduce_sub8(dpart);
        float qj = reduce_sub8(qpart);

        float sim = dj / fmaxf(na * sqrtf(qj), EPS) * TEMP_INV;
        e_acc += expf(sim - 10.0f);   // arg <= 0 always; in (0,1]
        p_acc += sim;
    }

    // combine the 8 per-sample values held by the j-groups (3 shuffles total)
    e_acc = reduce_grp8(e_acc);
    if (lane == 0) S_ws[c * B_ + b] = e_acc;   // [chunk][b] -> coalesced finalize reads

    if (c < 2) {
        float ps = reduce_grp8(p_acc);
        if (lane == 0) POS_ws[c * B_ + b] = ps;
    }
}

// One block, 256 threads (thread t = batch row b):
//   out = 10 + mean_b( log S_b ) - (sum of positive sims) / (B*P)
// Direct (non-atomic) write of out -> no dependence on poisoned output state.
__global__ __launch_bounds__(256) void finalize_kernel(
    const float* __restrict__ S_ws,
    const float* __restrict__ POS_ws,
    float* __restrict__ out)
{
    int t    = threadIdx.x;
    int wid  = t >> 6;
    int lane = t & 63;

    float s = 0.f;
    #pragma unroll
    for (int i = 0; i < NCHUNK_; i++) s += S_ws[i * B_ + t];   // coalesced
    float v  = logf(s);                         // log S_b   (LSE_b = 10 + v)
    float pp = POS_ws[t] + POS_ws[B_ + t];      // positive sim sum for row b

    float red = v * (1.0f / (float)B_) - pp * (1.0f / (float)(B_ * P_));
    #pragma unroll
    for (int m = 32; m >= 1; m >>= 1) red += __shfl_xor(red, m, 64);

    __shared__ float sh[4];
    if (lane == 0) sh[wid] = red;
    __syncthreads();
    if (t == 0) out[0] = 10.0f + (sh[0] + sh[1] + sh[2] + sh[3]);
}

extern "C" void kernel_launch(void* const* d_in, const int* in_sizes, int n_in,
                              void* d_out, int out_size, void* d_ws, size_t ws_size,
                              hipStream_t stream) {
    const float* anchors   = (const float*)d_in[0];
    const float* positives = (const float*)d_in[1];
    const float* negatives = (const float*)d_in[2];
    float* out = (float*)d_out;

    float* S_ws   = (float*)d_ws;                 // NCHUNK_*B_ floats (34 KB)
    float* POS_ws = S_ws + NCHUNK_ * B_;          // 2*B_ floats

    int n_waves  = B_ * NCHUNK_;                  // 8704, divisible by 4
    int n_blocks = n_waves / 4;                   // 2176 blocks x 4 waves
    partial_kernel<<<n_blocks, 256, 0, stream>>>(anchors, positives, negatives,
                                                 S_ws, POS_ws);
    finalize_kernel<<<1, 256, 0, stream>>>(S_ws, POS_ws, out);
}